// Round 14
// baseline (209.623 us; speedup 1.0000x reference)
//
#include <hip/hip_runtime.h>

#define LAT_SHAPE 1801
#define LON_SHAPE 3600
#define NPTS 2000000
#define NSTRIPE 226   // 8-row latitude stripes: ceil(1801/8)
#define HB 1024       // hist/scatter block size

typedef float f32x4 __attribute__((ext_vector_type(4)));
typedef float f32x2 __attribute__((ext_vector_type(2)));

// FROZEN MATH (bit-exact vs np golden, round 5): f32, *10.0f, ties-even.
__device__ __forceinline__ void coord2idx(float lat, float lon, int& yi, int& xi) {
    yi = (int)rintf((90.0f - lat) * 10.0f);
    xi = (int)rintf(lon * 10.0f);
    yi = min(max(yi, 0), LAT_SHAPE - 1);
    xi = min(max(xi, 0), LON_SHAPE - 1);
}

__device__ __forceinline__ f32x2 load_pair(const float* p) {
    f32x2 v; __builtin_memcpy(&v, p, 8); return v;
}

// ---- Pass A: per-block 226-bin stripe histogram (LDS only) ----
__global__ __launch_bounds__(HB) void hist_k(const float2* __restrict__ x, int n,
                                             int nblk, unsigned* __restrict__ cnt) {
    __shared__ unsigned h[NSTRIPE];
    for (int k = threadIdx.x; k < NSTRIPE; k += HB) h[k] = 0;
    __syncthreads();
    int i = blockIdx.x * HB + threadIdx.x;
    if (i < n) {
        float2 p = x[i];
        int yi, xi; coord2idx(p.x, p.y, yi, xi);
        atomicAdd(&h[yi >> 3], 1u);
    }
    __syncthreads();
    for (int k = threadIdx.x; k < NSTRIPE; k += HB)
        cnt[(size_t)k * nblk + blockIdx.x] = h[k];
}

// ---- Pass B1: per-stripe exclusive scan over blocks, in place ----
__global__ __launch_bounds__(256) void scanband_k(unsigned* __restrict__ cnt, int nblk,
                                                  unsigned* __restrict__ stripeTotal) {
    unsigned* a = cnt + (size_t)blockIdx.x * nblk;
    int chunk = (nblk + 255) / 256;
    int t = threadIdx.x;
    int lo = t * chunk, hi = min(nblk, lo + chunk);
    unsigned s = 0;
    for (int k = lo; k < hi; ++k) s += a[k];
    __shared__ unsigned ls[256];
    ls[t] = s;
    __syncthreads();
    for (int off = 1; off < 256; off <<= 1) {
        unsigned v = (t >= off) ? ls[t - off] : 0u;
        __syncthreads();
        ls[t] += v;
        __syncthreads();
    }
    unsigned run = (t == 0) ? 0u : ls[t - 1];
    for (int k = lo; k < hi; ++k) { unsigned v = a[k]; a[k] = run; run += v; }
    if (t == 255) stripeTotal[blockIdx.x] = ls[255];
}

// ---- Pass B2: stripe bases (226 values, serial) ----
__global__ void bandbase_k(const unsigned* __restrict__ stripeTotal,
                           unsigned* __restrict__ stripeBase) {
    if (threadIdx.x == 0) {
        unsigned acc = 0;
        for (int b = 0; b < NSTRIPE; ++b) { stripeBase[b] = acc; acc += stripeTotal[b]; }
        stripeBase[NSTRIPE] = acc;
    }
}

// ---- Pass C: scatter records into stripe order (no global atomics) ----
__global__ __launch_bounds__(HB) void scatter_k(const float2* __restrict__ x, int n,
                                                int nblk,
                                                const unsigned* __restrict__ cnt,
                                                const unsigned* __restrict__ stripeBase,
                                                uint2* __restrict__ rec) {
    __shared__ unsigned h[NSTRIPE];
    for (int k = threadIdx.x; k < NSTRIPE; k += HB) h[k] = 0;
    __syncthreads();
    int i = blockIdx.x * HB + threadIdx.x;
    if (i >= n) return;
    float2 p = x[i];
    int yi, xi; coord2idx(p.x, p.y, yi, xi);
    int b = yi >> 3;
    unsigned r = atomicAdd(&h[b], 1u);   // raced rank: output order-independent
    unsigned dest = stripeBase[b] + cnt[(size_t)b * nblk + blockIdx.x] + r;
    rec[dest] = make_uint2((unsigned)i, ((unsigned)yi << 12) | (unsigned)xi);
}

// ---- Pass D: main compute; in-LDS x-tile sort gives wave line-locality ----
__global__ __launch_bounds__(256) void main_k(
    const uint2* __restrict__ rec, int n, int nchunk,
    const float* __restrict__ g0, const float* __restrict__ g1,
    const float* __restrict__ g2, const float* __restrict__ g3,
    const float* __restrict__ g4, const float* __restrict__ g5,
    const float* __restrict__ g6, const float* __restrict__ g7,
    float* __restrict__ out)
{
#pragma clang fp contract(off)
    __shared__ float g6s[1653];
    __shared__ float g7s[435];
    __shared__ uint2 srt[256];
    __shared__ unsigned xh[57], xb[57];

    for (int k = threadIdx.x; k < 1653; k += 256) g6s[k] = g6[k];
    for (int k = threadIdx.x; k < 435; k += 256) g7s[k] = g7[k];

    // m204 bijective XCD swizzle over chunks (adjacent chunks share an L2).
    int orig = blockIdx.x;
    int xcd = orig & 7;
    int q = nchunk >> 3, rr = nchunk & 7;
    int chunk = (xcd < rr ? xcd * (q + 1) : rr * (q + 1) + (xcd - rr) * q) + (orig >> 3);
    int gbase = chunk * 256;
    int cn = min(256, n - gbase);      // tail chunk
    int t = threadIdx.x;

    if (t < 57) { xh[t] = 0; }
    __syncthreads();

    // Load my record; counting-sort the chunk by x-tile (64-col bins) so each
    // wave's 64 points are x-adjacent -> gather lanes share cache lines.
    unsigned myrank = 0; int myxt = 0; uint2 rc;
    if (t < cn) {
        rc = rec[gbase + t];
        myxt = (int)((rc.y & 4095u) >> 6);
        myrank = atomicAdd(&xh[myxt], 1u);
    }
    __syncthreads();
    if (t == 0) {
        unsigned acc = 0;
        for (int k = 0; k < 57; ++k) { xb[k] = acc; acc += xh[k]; }
    }
    __syncthreads();
    if (t < cn) srt[xb[myxt] + myrank] = rc;
    __syncthreads();

    if (t >= cn) return;
    uint2 rc2 = srt[t];
    int yi = (int)(rc2.y >> 12);
    int xi = (int)(rc2.y & 4095u);

    float res[8];
    res[0] = g0[yi * LON_SHAPE + xi];   // level 0: blend collapses to v00

    constexpr int H[5] = {901, 451, 226, 113, 57};
    constexpr int W[5] = {1800, 900, 450, 225, 113};
    constexpr float SCY[5] = {
        (float)(901.0 / 1801.0), (float)(451.0 / 1801.0), (float)(226.0 / 1801.0),
        (float)(113.0 / 1801.0), (float)(57.0 / 1801.0)};
    constexpr float SCX[5] = {
        (float)(1800.0 / 3600.0), (float)(900.0 / 3600.0), (float)(450.0 / 3600.0),
        (float)(225.0 / 3600.0), (float)(113.0 / 3600.0)};
    const float* gg[5] = {g1, g2, g3, g4, g5};
    const float yif = (float)yi, xif = (float)xi;

    f32x2 pa[5], pb[5];
    float wyA[5], wxA[5];
    bool hiA[5];
#pragma unroll
    for (int i = 0; i < 5; ++i) {
        float sy = fmaxf((yif + 0.5f) * SCY[i] - 0.5f, 0.0f);
        float sx = fmaxf((xif + 0.5f) * SCX[i] - 0.5f, 0.0f);
        int y0 = (int)sy, x0 = (int)sx;
        wyA[i] = sy - (float)y0;
        wxA[i] = sx - (float)x0;
        int y1 = min(y0 + 1, H[i] - 1);
        int xbp = min(x0, W[i] - 2);
        hiA[i] = x0 > xbp;
        const float* __restrict__ g = gg[i];
        pa[i] = load_pair(g + y0 * W[i] + xbp);
        pb[i] = load_pair(g + y1 * W[i] + xbp);
    }
    {   // LDS levels 6..7 while global pairs are in flight
        constexpr int HL[2] = {29, 15};
        constexpr int WL[2] = {57, 29};
        constexpr float LSY[2] = {(float)(29.0 / 1801.0), (float)(15.0 / 1801.0)};
        constexpr float LSX[2] = {(float)(57.0 / 3600.0), (float)(29.0 / 3600.0)};
#pragma unroll
        for (int i = 0; i < 2; ++i) {
            const float* g = (i == 0) ? g6s : g7s;
            float sy = fmaxf((yif + 0.5f) * LSY[i] - 0.5f, 0.0f);
            float sx = fmaxf((xif + 0.5f) * LSX[i] - 0.5f, 0.0f);
            int y0 = (int)sy, x0 = (int)sx;
            float wy = sy - (float)y0, wx = sx - (float)x0;
            int y1 = min(y0 + 1, HL[i] - 1), x1 = min(x0 + 1, WL[i] - 1);
            float v00 = g[y0 * WL[i] + x0], v01 = g[y0 * WL[i] + x1];
            float v10 = g[y1 * WL[i] + x0], v11 = g[y1 * WL[i] + x1];
            float omwy = 1.0f - wy, omwx = 1.0f - wx;
            res[6 + i] = v00 * omwy * omwx + v01 * omwy * wx
                       + v10 * wy * omwx + v11 * wy * wx;
        }
    }
#pragma unroll
    for (int i = 0; i < 5; ++i) {
        float v00 = hiA[i] ? pa[i].y : pa[i].x;
        float v01 = pa[i].y;
        float v10 = hiA[i] ? pb[i].y : pb[i].x;
        float v11 = pb[i].y;
        float wy = wyA[i], wx = wxA[i];
        float omwy = 1.0f - wy, omwx = 1.0f - wx;
        res[1 + i] = v00 * omwy * omwx + v01 * omwy * wx
                   + v10 * wy * omwx + v11 * wy * wx;
    }

    float* op = out + (size_t)rc2.x * 8;   // 32B-aligned: one granule/point
    f32x4 lo = {res[0], res[1], res[2], res[3]};
    f32x4 hi = {res[4], res[5], res[6], res[7]};
    __builtin_nontemporal_store(lo, (f32x4*)op);
    __builtin_nontemporal_store(hi, (f32x4*)(op + 4));
}

// ---- Fallback: round-7 direct kernel (145us, verified) ----
__global__ __launch_bounds__(256) void le_kernel(
    const float2* __restrict__ x,
    const float* __restrict__ g0, const float* __restrict__ g1,
    const float* __restrict__ g2, const float* __restrict__ g3,
    const float* __restrict__ g4, const float* __restrict__ g5,
    const float* __restrict__ g6, const float* __restrict__ g7,
    float* __restrict__ out, int n)
{
#pragma clang fp contract(off)
    __shared__ float g6s[1653];
    __shared__ float g7s[435];
    __shared__ f32x4 obuf[512];
    for (int k = threadIdx.x; k < 1653; k += 256) g6s[k] = g6[k];
    for (int k = threadIdx.x; k < 435; k += 256) g7s[k] = g7[k];
    __syncthreads();
    int idx = blockIdx.x * blockDim.x + threadIdx.x;
    int cidx = min(idx, n - 1);
    float2 p = x[cidx];
    int yi, xi; coord2idx(p.x, p.y, yi, xi);
    float res[8];
    res[0] = g0[yi * LON_SHAPE + xi];
    constexpr int H[8] = {1801, 901, 451, 226, 113, 57, 29, 15};
    constexpr int W[8] = {3600, 1800, 900, 450, 225, 113, 57, 29};
    const float yif = (float)yi, xif = (float)xi;
    auto bilin = [&](auto g, int Hi, int Wi, float sy_scale, float sx_scale) -> float {
#pragma clang fp contract(off)
        float sy = fmaxf((yif + 0.5f) * sy_scale - 0.5f, 0.0f);
        float sx = fmaxf((xif + 0.5f) * sx_scale - 0.5f, 0.0f);
        int y0 = (int)sy; int x0 = (int)sx;
        float wy = sy - (float)y0; float wx = sx - (float)x0;
        int y1 = min(y0 + 1, Hi - 1); int x1 = min(x0 + 1, Wi - 1);
        float v00 = g[y0 * Wi + x0]; float v01 = g[y0 * Wi + x1];
        float v10 = g[y1 * Wi + x0]; float v11 = g[y1 * Wi + x1];
        float omwy = 1.0f - wy, omwx = 1.0f - wx;
        return v00 * omwy * omwx + v01 * omwy * wx + v10 * wy * omwx + v11 * wy * wx;
    };
#define SC(i, dim, tot) ((float)((double)dim[i] / (double)tot))
    res[1] = bilin(g1, H[1], W[1], SC(1, H, LAT_SHAPE), SC(1, W, LON_SHAPE));
    res[2] = bilin(g2, H[2], W[2], SC(2, H, LAT_SHAPE), SC(2, W, LON_SHAPE));
    res[3] = bilin(g3, H[3], W[3], SC(3, H, LAT_SHAPE), SC(3, W, LON_SHAPE));
    res[4] = bilin(g4, H[4], W[4], SC(4, H, LAT_SHAPE), SC(4, W, LON_SHAPE));
    res[5] = bilin(g5, H[5], W[5], SC(5, H, LAT_SHAPE), SC(5, W, LON_SHAPE));
    res[6] = bilin((const float*)g6s, H[6], W[6], SC(6, H, LAT_SHAPE), SC(6, W, LON_SHAPE));
    res[7] = bilin((const float*)g7s, H[7], W[7], SC(7, H, LAT_SHAPE), SC(7, W, LON_SHAPE));
#undef SC
    f32x4 lo = {res[0], res[1], res[2], res[3]};
    f32x4 hi = {res[4], res[5], res[6], res[7]};
    obuf[2 * threadIdx.x] = lo;
    obuf[2 * threadIdx.x + 1] = hi;
    __syncthreads();
    const size_t total_f4 = (size_t)n * 2;
    const size_t base = (size_t)blockIdx.x * 512;
    f32x4* o4 = (f32x4*)out;
    int t = threadIdx.x;
    if (base + t < total_f4) __builtin_nontemporal_store(obuf[t], &o4[base + t]);
    if (base + 256 + t < total_f4) __builtin_nontemporal_store(obuf[256 + t], &o4[base + 256 + t]);
}

extern "C" void kernel_launch(void* const* d_in, const int* in_sizes, int n_in,
                              void* d_out, int out_size, void* d_ws, size_t ws_size,
                              hipStream_t stream) {
    const int GSZ[8] = {6483600, 1621800, 405900, 101700, 25425, 6441, 1653, 435};
    const float* xp = nullptr;
    const float* g[8] = {nullptr};
    int n = 0;
    for (int i = 0; i < n_in; ++i) {
        int s = in_sizes[i];
        if (s == 2 * NPTS) { xp = (const float*)d_in[i]; n = NPTS; continue; }
        for (int l = 0; l < 8; ++l)
            if (s == GSZ[l]) { g[l] = (const float*)d_in[i]; break; }
    }
    if (!xp) { xp = (const float*)d_in[0]; n = in_sizes[0] / 2; }
    for (int l = 0; l < 8; ++l)
        if (!g[l]) g[l] = (const float*)d_in[1 + l];

    const float2* x2 = (const float2*)xp;
    float* out = (float*)d_out;
    int nblk = (n + HB - 1) / HB;
    int nchunk = (n + 255) / 256;

    // ws layout: stripeTotal[226] @0 | stripeBase[227] @4KB | cnt @8KB | rec
    size_t cntBytes = (size_t)NSTRIPE * nblk * 4;
    size_t recOff = (8192 + cntBytes + 255) & ~(size_t)255;
    size_t need = recOff + (size_t)n * 8;

    if (n > 0 && ws_size >= need) {
        unsigned* stripeTotal = (unsigned*)d_ws;
        unsigned* stripeBase = (unsigned*)((char*)d_ws + 4096);
        unsigned* cnt = (unsigned*)((char*)d_ws + 8192);
        uint2* rec = (uint2*)((char*)d_ws + recOff);
        hist_k<<<nblk, HB, 0, stream>>>(x2, n, nblk, cnt);
        scanband_k<<<NSTRIPE, 256, 0, stream>>>(cnt, nblk, stripeTotal);
        bandbase_k<<<1, 64, 0, stream>>>(stripeTotal, stripeBase);
        scatter_k<<<nblk, HB, 0, stream>>>(x2, n, nblk, cnt, stripeBase, rec);
        main_k<<<nchunk, 256, 0, stream>>>(rec, n, nchunk, g[0], g[1], g[2], g[3],
                                           g[4], g[5], g[6], g[7], out);
    } else {
        le_kernel<<<(n + 255) / 256, 256, 0, stream>>>(x2, g[0], g[1], g[2], g[3],
                                                       g[4], g[5], g[6], g[7], out, n);
    }
}

// Round 15
// 183.067 us; speedup vs baseline: 1.1451x; 1.1451x over previous
//
#include <hip/hip_runtime.h>

#define LAT_SHAPE 1801
#define LON_SHAPE 3600
#define NPTS 2000000

typedef float f32x4 __attribute__((ext_vector_type(4)));

__global__ __launch_bounds__(256) void le_kernel(
    const float2* __restrict__ x,
    const float* __restrict__ g0, const float* __restrict__ g1,
    const float* __restrict__ g2, const float* __restrict__ g3,
    const float* __restrict__ g4, const float* __restrict__ g5,
    const float* __restrict__ g6, const float* __restrict__ g7,
    float* __restrict__ out, int n)
{
#pragma clang fp contract(off)
    // Only LDS use: output packing buffer (8KB). g6/g7 are NOT staged —
    // they are 6.6KB/1.7KB and live in L1 after warmup; staging cost 2088
    // loads + a vmcnt-draining barrier per block (guide: Common-mistake #7).
    __shared__ f32x4 obuf[512];

    int idx = blockIdx.x * blockDim.x + threadIdx.x;
    int cidx = min(idx, n - 1);   // tail threads duplicate last point
    float2 p = x[cidx];

    // FROZEN MATH (bit-exact vs np golden, round 5): f32, *10.0f, ties-even.
    int yi = (int)rintf((90.0f - p.x) * 10.0f);
    int xi = (int)rintf(p.y * 10.0f);
    yi = min(max(yi, 0), LAT_SHAPE - 1);
    xi = min(max(xi, 0), LON_SHAPE - 1);

    float res[8];

    // Level 0: scale exactly 1.0 -> blend collapses to v00. Single gather.
    res[0] = g0[yi * LON_SHAPE + xi];

    constexpr int H[8] = {1801, 901, 451, 226, 113, 57, 29, 15};
    constexpr int W[8] = {3600, 1800, 900, 450, 225, 113, 57, 29};

    const float yif = (float)yi;
    const float xif = (float)xi;

    auto bilin = [&](const float* __restrict__ g, int Hi, int Wi,
                     float sy_scale, float sx_scale) -> float {
#pragma clang fp contract(off)
        float sy = fmaxf((yif + 0.5f) * sy_scale - 0.5f, 0.0f);
        float sx = fmaxf((xif + 0.5f) * sx_scale - 0.5f, 0.0f);
        int y0 = (int)sy;   // floor: sy >= 0
        int x0 = (int)sx;
        float wy = sy - (float)y0;
        float wx = sx - (float)x0;
        int y1 = min(y0 + 1, Hi - 1);
        int x1 = min(x0 + 1, Wi - 1);
        float v00 = g[y0 * Wi + x0];
        float v01 = g[y0 * Wi + x1];
        float v10 = g[y1 * Wi + x0];
        float v11 = g[y1 * Wi + x1];
        float omwy = 1.0f - wy, omwx = 1.0f - wx;
        return v00 * omwy * omwx + v01 * omwy * wx
             + v10 * wy * omwx + v11 * wy * wx;
    };

#define SC(i, dim, tot) ((float)((double)dim[i] / (double)tot))
    res[1] = bilin(g1, H[1], W[1], SC(1, H, LAT_SHAPE), SC(1, W, LON_SHAPE));
    res[2] = bilin(g2, H[2], W[2], SC(2, H, LAT_SHAPE), SC(2, W, LON_SHAPE));
    res[3] = bilin(g3, H[3], W[3], SC(3, H, LAT_SHAPE), SC(3, W, LON_SHAPE));
    res[4] = bilin(g4, H[4], W[4], SC(4, H, LAT_SHAPE), SC(4, W, LON_SHAPE));
    res[5] = bilin(g5, H[5], W[5], SC(5, H, LAT_SHAPE), SC(5, W, LON_SHAPE));
    res[6] = bilin(g6, H[6], W[6], SC(6, H, LAT_SHAPE), SC(6, W, LON_SHAPE));
    res[7] = bilin(g7, H[7], W[7], SC(7, H, LAT_SHAPE), SC(7, W, LON_SHAPE));
#undef SC

    // Pack 8 floats/point through LDS so each store instruction covers a
    // fully-contiguous 1KB range (round-7 verified: WRITE_SIZE 120->62.5MB).
    f32x4 lo = {res[0], res[1], res[2], res[3]};
    f32x4 hi = {res[4], res[5], res[6], res[7]};
    obuf[2 * threadIdx.x]     = lo;
    obuf[2 * threadIdx.x + 1] = hi;
    __syncthreads();

    const size_t total_f4 = (size_t)n * 2;
    const size_t base = (size_t)blockIdx.x * 512;
    f32x4* o4 = (f32x4*)out;
    int t = threadIdx.x;
    if (base + t < total_f4)
        __builtin_nontemporal_store(obuf[t], &o4[base + t]);
    if (base + 256 + t < total_f4)
        __builtin_nontemporal_store(obuf[256 + t], &o4[base + 256 + t]);
}

extern "C" void kernel_launch(void* const* d_in, const int* in_sizes, int n_in,
                              void* d_out, int out_size, void* d_ws, size_t ws_size,
                              hipStream_t stream) {
    // Assign roles by unique element count (robust to input permutation).
    const int GSZ[8] = {6483600, 1621800, 405900, 101700, 25425, 6441, 1653, 435};
    const float* xp = nullptr;
    const float* g[8] = {nullptr};
    int n = 0;
    for (int i = 0; i < n_in; ++i) {
        int s = in_sizes[i];
        if (s == 2 * NPTS) { xp = (const float*)d_in[i]; n = NPTS; continue; }
        for (int l = 0; l < 8; ++l)
            if (s == GSZ[l]) { g[l] = (const float*)d_in[i]; break; }
    }
    if (!xp) { xp = (const float*)d_in[0]; n = in_sizes[0] / 2; }
    for (int l = 0; l < 8; ++l)
        if (!g[l]) g[l] = (const float*)d_in[1 + l];

    int blocks = (n + 255) / 256;
    le_kernel<<<blocks, 256, 0, stream>>>((const float2*)xp, g[0], g[1], g[2],
                                          g[3], g[4], g[5], g[6], g[7],
                                          (float*)d_out, n);
}